// Round 3
// baseline (992.096 us; speedup 1.0000x reference)
//
#include <hip/hip_runtime.h>

typedef unsigned short u16;
typedef __attribute__((ext_vector_type(8))) short bf16x8;   // 8 bf16 = 4 VGPRs (MFMA A/B frag)
typedef __attribute__((ext_vector_type(4))) float f32x4;    // MFMA C/D frag

// ---------- constants ----------
#define TSEQ 32      // LSTM time steps (reshape bug: seq runs over B)
#define NB   128     // LSTM batch
#define HDIM 400
#define KPAD 416     // 400 padded to 13*32 for MFMA K
#define G4   1600    // 4*H
#define TOK  4096    // 32*128 tokens

__device__ __forceinline__ float b2f(u16 u) {
  union { unsigned int i; float f; } v; v.i = ((unsigned int)u) << 16; return v.f;
}
__device__ __forceinline__ u16 f2b(float f) {
  union { float fl; unsigned int i; } v; v.fl = f;
  unsigned int r = v.i + 0x7fffu + ((v.i >> 16) & 1u);   // RNE
  return (u16)(r >> 16);
}
// dtype-agnostic loads: isbf=1 -> buffer is bf16, else fp32
__device__ __forceinline__ float loadf(const void* p, long long i, int isbf) {
  return isbf ? b2f(((const u16*)p)[i]) : ((const float*)p)[i];
}
__device__ __forceinline__ u16 loadb(const void* p, long long i, int isbf) {
  return isbf ? ((const u16*)p)[i] : f2b(((const float*)p)[i]);
}
__device__ __forceinline__ float sigm_(float x) { return 1.0f / (1.0f + __expf(-x)); }
__device__ __forceinline__ float tanh_(float x) {
  float e = __expf(2.0f * x);
  return 1.0f - 2.0f / (e + 1.0f);   // exact limits at +-inf, no NaN
}

// ---------- input dtype sniffer ----------
__global__ __launch_bounds__(256) void sniff_kernel(const void* wemb, int* flag) {
  __shared__ int cf, cb;
  if (threadIdx.x == 0) { cf = 0; cb = 0; }
  __syncthreads();
  int okf = 0, okb = 0;
  for (int i = threadIdx.x; i < 8192; i += 256) {
    float f = ((const float*)wemb)[i];
    float af = fabsf(f);
    if (af > 1e-12f && af < 8.0f) okf++;
    u16 ub = ((const u16*)wemb)[i];
    float fb = b2f(ub); float ab = fabsf(fb);
    if (ub == 0 || (ab > 1e-12f && ab < 8.0f)) okb++;
  }
  atomicAdd(&cf, okf);
  atomicAdd(&cb, okb);
  __syncthreads();
  if (threadIdx.x == 0) flag[0] = (cb > cf) ? 1 : 0;
}

// ---------- embedding + faithful reshape ----------
// XP[t*128+n, d] = concat(word_emb, tag_emb)[flat row n*32+t]  (the view(L,B,-1) bug)
__global__ __launch_bounds__(256) void embed_kernel(
    const int* __restrict__ words, const int* __restrict__ tags,
    const void* __restrict__ wemb, const void* __restrict__ temb,
    const int* __restrict__ flag, u16* __restrict__ XP) {
  const int isbf = flag[0];
  int idx = blockIdx.x * 256 + threadIdx.x;      // 4096*400
  if (idx >= TOK * 400) return;
  int r = idx / 400, d = idx - r * 400;
  int t = r >> 7, n = r & 127;
  int m = n * 32 + t;                            // flat row of embeds (B,L,400)
  int b = m >> 7, l = m & 127;
  u16 v;
  if (d < 300) v = loadb(wemb, (long long)words[b * 128 + l] * 300 + d, isbf);
  else         v = loadb(temb, (long long)tags[b * 128 + l] * 100 + (d - 300), isbf);
  XP[(size_t)r * KPAD + d] = v;                  // pad cols [400,416) pre-zeroed by memset
}

// ---------- weight pre-arrangement ----------
__global__ __launch_bounds__(256) void prep_kernel(
    const void* wih0, const void* wih1, const void* wih2, const void* wih3,
    const void* whhA0, const void* whhA1, const void* whhA2, const void* whhA3,
    const void* bih0, const void* bih1, const void* bih2, const void* bih3,
    const void* bhh0, const void* bhh1, const void* bhh2, const void* bhh3,
    const void* w1, const void* b1, const void* w2, const void* b2,
    const int* __restrict__ flag,
    u16* __restrict__ W0a, u16* __restrict__ W1a, u16* __restrict__ WhhA,
    float* __restrict__ biasA, u16* __restrict__ W1ab, float* __restrict__ smallf) {
  const int isbf = flag[0];
  long long idx = (long long)blockIdx.x * 256 + threadIdx.x;
  const void* wihs[4] = {wih0, wih1, wih2, wih3};
  const void* whhs[4] = {whhA0, whhA1, whhA2, whhA3};
  const void* bihs[4] = {bih0, bih1, bih2, bih3};
  const void* bhhs[4] = {bhh0, bhh1, bhh2, bhh3};
  const long long c1 = 1331200LL, c2 = 3891200LL, c3 = 6553600LL, c4 = 6560000LL,
                  c5 = 6726400LL, c6 = 6726601LL;
  if (idx < c1) {                       // W0a: [2][1600][416]
    int j = (int)idx; int row = j / KPAD; int k = j - row * KPAD;
    int dir = row / G4; int ar = row - dir * G4;
    int ct = ar >> 6, rem = ar & 63, ty = rem >> 4, jj = rem & 15;
    int srow = ty * 400 + ct * 16 + jj;
    W0a[j] = (k < 400) ? loadb(wihs[dir], (long long)srow * 400 + k, isbf) : (u16)0;
  } else if (idx < c2) {                // W1a: [2][1600][800]
    int j = (int)(idx - c1); int row = j / 800; int k = j - row * 800;
    int dir = row / G4; int ar = row - dir * G4;
    int ct = ar >> 6, rem = ar & 63, ty = rem >> 4, jj = rem & 15;
    int srow = ty * 400 + ct * 16 + jj;
    W1a[j] = loadb(wihs[2 + dir], (long long)srow * 800 + k, isbf);
  } else if (idx < c3) {                // WhhA: [4][1600][416]
    int j = (int)(idx - c2); int row = j / KPAD; int k = j - row * KPAD;
    int dl = row / G4; int ar = row - dl * G4;
    int ct = ar >> 6, rem = ar & 63, ty = rem >> 4, jj = rem & 15;
    int srow = ty * 400 + ct * 16 + jj;
    WhhA[j] = (k < 400) ? loadb(whhs[dl], (long long)srow * 400 + k, isbf) : (u16)0;
  } else if (idx < c4) {                // biasA: [4][1600]
    int j = (int)(idx - c3); int dl = j / G4; int ar = j - dl * G4;
    int ct = ar >> 6, rem = ar & 63, ty = rem >> 4, jj = rem & 15;
    int srow = ty * 400 + ct * 16 + jj;
    biasA[j] = loadf(bihs[dl], srow, isbf) + loadf(bhhs[dl], srow, isbf);
  } else if (idx < c5) {                // W1ab: [208][800]
    int j = (int)(idx - c4); int row = j / 800; int k = j - row * 800;
    u16 v = 0;
    if (row < 100)      v = loadb(w1, (long long)row * 1600 + k, isbf);
    else if (row < 200) v = loadb(w1, (long long)(row - 100) * 1600 + 800 + k, isbf);
    W1ab[j] = v;
  } else if (idx < c6) {                // smallf: b1(100), w2(100), b2(1)
    int j = (int)(idx - c5);
    if (j < 100)       smallf[j] = loadf(b1, j, isbf);
    else if (j < 200)  smallf[j] = loadf(w2, j - 100, isbf);
    else               smallf[200] = loadf(b2, 0, isbf);
  }
}

// ---------- one fused LSTM step (input transform + recurrence, both dirs) ----------
__global__ __launch_bounds__(256) void lstm_step_fused(
    const u16* __restrict__ Xsrc, const int xk,
    const u16* __restrict__ Wih, const u16* __restrict__ Whh,
    const float* __restrict__ bias,
    const u16* __restrict__ h_in, u16* __restrict__ h_out,
    float* __restrict__ c_state, u16* __restrict__ h_cat, const int s) {
  __shared__ u16 As[64 * 40];
  __shared__ u16 Bs[64 * 40];
  __shared__ float gs[64 * 68];
  const int ctile = blockIdx.x, ntile = blockIdx.y, dir = blockIdx.z;
  const int t = dir ? (31 - s) : s;
  const int n0 = ntile * 64, ar0 = ctile * 64;
  const int tid = threadIdx.x;
  const int wave = tid >> 6, lane = tid & 63;
  const int wr = wave >> 1, wc = wave & 1;
  const int srow = tid >> 2, sseg = tid & 3;
  const int KT = xk + KPAD;
  const u16* hbase = h_in + (size_t)dir * NB * KPAD;
  const u16* wi = Wih + (size_t)dir * G4 * xk;
  const u16* wh = Whh + (size_t)dir * G4 * KPAD;
  const size_t ax = (size_t)(t * 128 + n0 + srow) * xk + sseg * 8;
  const size_t ah = (size_t)(n0 + srow) * KPAD + sseg * 8;
  const size_t bx = (size_t)(ar0 + srow) * xk + sseg * 8;
  const size_t bh = (size_t)(ar0 + srow) * KPAD + sseg * 8;
  float4 ra = *(const float4*)&Xsrc[ax];
  float4 rb = *(const float4*)&wi[bx];
  f32x4 acc[2][2] = {};
  const int fr = lane & 15, fkb = (lane >> 4) * 8;
  for (int k0 = 32;; k0 += 32) {
    __syncthreads();
    *(float4*)&As[srow * 40 + sseg * 8] = ra;
    *(float4*)&Bs[srow * 40 + sseg * 8] = rb;
    bool more = k0 < KT;
    if (more) {
      ra = (k0 < xk) ? *(const float4*)&Xsrc[ax + k0] : *(const float4*)&hbase[ah + (k0 - xk)];
      rb = (k0 < xk) ? *(const float4*)&wi[bx + k0]   : *(const float4*)&wh[bh + (k0 - xk)];
    }
    __syncthreads();
    bf16x8 af[2], bf[2];
#pragma unroll
    for (int i = 0; i < 2; i++) af[i] = *(const bf16x8*)&As[(wr * 32 + i * 16 + fr) * 40 + fkb];
#pragma unroll
    for (int j = 0; j < 2; j++) bf[j] = *(const bf16x8*)&Bs[(wc * 32 + j * 16 + fr) * 40 + fkb];
#pragma unroll
    for (int i = 0; i < 2; i++)
#pragma unroll
      for (int j = 0; j < 2; j++)
        acc[i][j] = __builtin_amdgcn_mfma_f32_16x16x32_bf16(af[i], bf[j], acc[i][j], 0, 0, 0);
    if (!more) break;
  }
  const int rg = lane >> 4;
#pragma unroll
  for (int i = 0; i < 2; i++)
#pragma unroll
    for (int j = 0; j < 2; j++)
#pragma unroll
      for (int r = 0; r < 4; r++)
        gs[(wr * 32 + i * 16 + rg * 4 + r) * 68 + wc * 32 + j * 16 + fr] = acc[i][j][r];
  __syncthreads();
  for (int it = tid; it < 1024; it += 256) {
    int nl = it >> 4, j = it & 15;
    int n = n0 + nl;
    int row = t * 128 + n;
    int bb = dir * G4 + ar0 + j;
    float gi = gs[nl * 68 + j]      + bias[bb];
    float gf = gs[nl * 68 + 16 + j] + bias[bb + 16];
    float gg = gs[nl * 68 + 32 + j] + bias[bb + 32];
    float go = gs[nl * 68 + 48 + j] + bias[bb + 48];
    int cidx = ctile * 16 + j;
    float* cp = &c_state[((size_t)dir * NB + n) * HDIM + cidx];
    float c_old = *cp;
    float c_new = sigm_(gf) * c_old + sigm_(gi) * tanh_(gg);
    float h_new = sigm_(go) * tanh_(c_new);
    *cp = c_new;
    u16 hb = f2b(h_new);
    h_out[((size_t)dir * NB + n) * KPAD + cidx] = hb;
    h_cat[(size_t)row * 800 + dir * HDIM + cidx] = hb;
  }
}

// ---------- a/bm projection ----------
__global__ __launch_bounds__(256) void ab_gemm(
    const u16* __restrict__ h1, const u16* __restrict__ W1ab,
    const float* __restrict__ smallf, float* __restrict__ abuf, float* __restrict__ bbuf) {
  int lane = threadIdx.x & 63, wv = threadIdx.x >> 6;
  int mt = blockIdx.y * 4 + wv;
  int nt = blockIdx.x;
  int r0 = mt * 16, c0 = nt * 16;
  f32x4 acc = {};
  int fr = lane & 15, fk8 = (lane >> 4) * 8;
  for (int k0 = 0; k0 < 800; k0 += 32) {
    bf16x8 a = *(const bf16x8*)&h1[(size_t)(r0 + fr) * 800 + k0 + fk8];
    bf16x8 b = *(const bf16x8*)&W1ab[(size_t)(c0 + fr) * 800 + k0 + fk8];
    acc = __builtin_amdgcn_mfma_f32_16x16x32_bf16(a, b, acc, 0, 0, 0);
  }
  int c = c0 + fr;
  if (c < 200) {
#pragma unroll
    for (int r = 0; r < 4; r++) {
      int row = r0 + (lane >> 4) * 4 + r;
      int t = row >> 7, n = row & 127;
      int orow = n * 32 + t;
      float v = acc[r];
      if (c < 100) abuf[(size_t)orow * 100 + c] = v;
      else         bbuf[(size_t)orow * 100 + (c - 100)] = v + smallf[c - 100];
    }
  }
}

// ---------- fused pairwise MLP ----------
__global__ __launch_bounds__(256) void pairwise(
    const float* __restrict__ abuf, const float* __restrict__ bbuf,
    const float* __restrict__ smallf, const int* __restrict__ flag,
    void* __restrict__ outp) {
  __shared__ float aS[16 * 101];
  __shared__ float bS[16 * 101];
  __shared__ float w2S[104];
  int b = blockIdx.z, i0 = blockIdx.y * 16, j0 = blockIdx.x * 16;
  int tid = threadIdx.x;
  for (int idx = tid; idx < 1600; idx += 256) {
    int r = idx / 100, h = idx - r * 100;
    aS[r * 101 + h] = abuf[((size_t)(i0 + r) * 32 + b) * 100 + h];
    bS[r * 101 + h] = bbuf[((size_t)(j0 + r) * 32 + b) * 100 + h];
  }
  if (tid < 100) w2S[tid] = smallf[100 + tid];
  __syncthreads();
  float bias2 = smallf[200];
  int di = tid >> 4, dj = tid & 15;
  const float* ar = &aS[di * 101];
  const float* br = &bS[dj * 101];
  float s = 0.0f;
#pragma unroll 4
  for (int h = 0; h < 100; h++) s += w2S[h] * tanh_(ar[h] + br[h]);
  int i = i0 + di, j = j0 + dj;
  size_t pos = ((size_t)(i * 128 + j)) * 32 + b;
  float v = s + bias2;
  if (flag[0]) ((u16*)outp)[pos] = f2b(v);
  else         ((float*)outp)[pos] = v;
}

// ---------- host ----------
extern "C" void kernel_launch(void* const* d_in, const int* in_sizes, int n_in,
                              void* d_out, int out_size, void* d_ws, size_t ws_size,
                              hipStream_t stream) {
  (void)in_sizes; (void)n_in; (void)out_size; (void)ws_size;
  const int* words = (const int*)d_in[0];
  const int* tags  = (const int*)d_in[1];
  const void* wemb = d_in[4];
  const void* temb = d_in[5];
  const void* wih[4] = {d_in[6],  d_in[10], d_in[14], d_in[18]};
  const void* whh[4] = {d_in[7],  d_in[11], d_in[15], d_in[19]};
  const void* bih[4] = {d_in[8],  d_in[12], d_in[16], d_in[20]};
  const void* bhh[4] = {d_in[9],  d_in[13], d_in[17], d_in[21]};
  const void* w1 = d_in[22];
  const void* b1 = d_in[23];
  const void* w2 = d_in[24];
  const void* b2 = d_in[25];

  char* ws = (char*)d_ws;
  size_t off = 0;
  auto alloc = [&](size_t bytes) -> void* {
    void* p = ws + off; off = (off + bytes + 255) & ~(size_t)255; return p;
  };
  int*   flag  = (int*)  alloc(256);
  u16*   hstate= (u16*)  alloc((size_t)2 * 2 * NB * KPAD * 2);
  float* cstate= (float*)alloc((size_t)2 * NB * HDIM * 4);
  float* smallf= (float*)alloc(201 * 4);
  float* abuf  = (float*)alloc((size_t)TOK * 100 * 4);
  float* bbuf  = (float*)alloc((size_t)TOK * 100 * 4);
  u16*   hcat0 = (u16*)  alloc((size_t)TOK * 800 * 2);
  u16*   hcat1 = (u16*)  alloc((size_t)TOK * 800 * 2);
  u16*   XP    = (u16*)  alloc((size_t)TOK * KPAD * 2);
  u16*   W0a   = (u16*)  alloc((size_t)2 * G4 * KPAD * 2);
  u16*   W1a   = (u16*)  alloc((size_t)2 * G4 * 800 * 2);
  u16*   WhhA  = (u16*)  alloc((size_t)4 * G4 * KPAD * 2);
  float* biasA = (float*)alloc((size_t)4 * G4 * 4);
  u16*   W1ab  = (u16*)  alloc((size_t)208 * 800 * 2);

  const size_t stateBytes = (size_t)2 * 2 * NB * KPAD * 2 + (size_t)2 * NB * HDIM * 4;

  sniff_kernel<<<1, 256, 0, stream>>>(wemb, flag);
  hipMemsetAsync(XP, 0, (size_t)TOK * KPAD * 2, stream);
  prep_kernel<<<26276, 256, 0, stream>>>(
      wih[0], wih[1], wih[2], wih[3], whh[0], whh[1], whh[2], whh[3],
      bih[0], bih[1], bih[2], bih[3], bhh[0], bhh[1], bhh[2], bhh[3],
      w1, b1, w2, b2, flag, W0a, W1a, WhhA, biasA, W1ab, smallf);
  embed_kernel<<<6400, 256, 0, stream>>>(words, tags, wemb, temb, flag, XP);

  for (int layer = 0; layer < 2; layer++) {
    hipMemsetAsync(hstate, 0, stateBytes, stream);
    const u16* Xs   = layer ? hcat0 : XP;
    const int  xk   = layer ? 800 : KPAD;
    const u16* WihL = layer ? W1a : W0a;
    const u16* WhhL = WhhA + (size_t)layer * 2 * G4 * KPAD;
    const float* biasL = biasA + (size_t)layer * 2 * G4;
    u16* hc = layer ? hcat1 : hcat0;
    for (int s = 0; s < TSEQ; s++) {
      u16* hin  = hstate + (size_t)(s & 1) * 2 * NB * KPAD;
      u16* hout = hstate + (size_t)((s + 1) & 1) * 2 * NB * KPAD;
      lstm_step_fused<<<dim3(25, 2, 2), 256, 0, stream>>>(
          Xs, xk, WihL, WhhL, biasL, hin, hout, cstate, hc, s);
    }
  }

  ab_gemm<<<dim3(13, 64), 256, 0, stream>>>(hcat1, W1ab, smallf, abuf, bbuf);
  pairwise<<<dim3(8, 8, 32), 256, 0, stream>>>(abuf, bbuf, smallf, flag, d_out);
}